// Round 1
// baseline (742.421 us; speedup 1.0000x reference)
//
#include <hip/hip_runtime.h>

// Problem constants derived at launch from in_sizes:
// in[0]=x [B,TF,T], in[1]=gene_ids [T], in[2]=w_sub [TF,T], in[3]=b_sub [G],
// in[4]=edge_index [2,2E], in[5]=w_conv [1,2], in[6]=b_conv [2],
// in[7]=w_out [2G,3], in[8]=b_out [3]
// d_out = x_cat [B,G] ++ g [B,2G] ++ out [B,3]  (float32)

// ---------------- Stage 1: per-gene subnet dot + segment scatter ----------------
// z[b,t] = sum_tf x[b,tf,t]*w_sub[tf,t];  acc[b, gene_ids[t]] += z[b,t]
__global__ void k_subnet(const float* __restrict__ x, const float* __restrict__ w_sub,
                         const int* __restrict__ gene_ids, float* __restrict__ acc,
                         int TF, int T, int G) {
    int t = (blockIdx.x * blockDim.x + threadIdx.x) * 4;
    int b = blockIdx.y;
    if (t >= T) return;
    const size_t xbase = (size_t)b * TF * T;
    if (t + 3 < T && (T % 4) == 0) {
        const float4* xp = (const float4*)(x + xbase + t);
        const float4* wp = (const float4*)(w_sub + t);
        const size_t strideV = (size_t)T / 4;
        float4 a = make_float4(0.f, 0.f, 0.f, 0.f);
        #pragma unroll 8
        for (int tf = 0; tf < TF; ++tf) {
            float4 xv = xp[(size_t)tf * strideV];
            float4 wv = wp[(size_t)tf * strideV];
            a.x += xv.x * wv.x;
            a.y += xv.y * wv.y;
            a.z += xv.z * wv.z;
            a.w += xv.w * wv.w;
        }
        int g0 = gene_ids[t], g1 = gene_ids[t + 1], g2 = gene_ids[t + 2], g3 = gene_ids[t + 3];
        float* base = acc + (size_t)b * G;
        // merge adjacent columns belonging to the same gene before atomics
        float v = a.x; int cg = g0;
        if (g1 == cg) v += a.y; else { atomicAdd(base + cg, v); cg = g1; v = a.y; }
        if (g2 == cg) v += a.z; else { atomicAdd(base + cg, v); cg = g2; v = a.z; }
        if (g3 == cg) v += a.w; else { atomicAdd(base + cg, v); cg = g3; v = a.w; }
        atomicAdd(base + cg, v);
    } else {
        // scalar tail (not taken for T % 4 == 0, kept for generality)
        for (int tt = t; tt < T && tt < t + 4; ++tt) {
            float a = 0.f;
            for (int tf = 0; tf < TF; ++tf)
                a += x[xbase + (size_t)tf * T + tt] * w_sub[(size_t)tf * T + tt];
            atomicAdd(acc + (size_t)b * G + gene_ids[tt], a);
        }
    }
}

// ---------------- Stage 2: x_cat = relu(acc + b_sub) -> d_out[0 : B*G) ----------------
__global__ void k_xcat(const float* __restrict__ acc, const float* __restrict__ b_sub,
                       float* __restrict__ xcat, int BG, int G) {
    int i = blockIdx.x * blockDim.x + threadIdx.x;
    if (i >= BG) return;
    int g = i % G;
    float v = acc[i] + b_sub[g];
    xcat[i] = v > 0.f ? v : 0.f;
}

// ---------------- Stage 3: degree count over dst row ----------------
__global__ void k_deg(const int* __restrict__ ei, float* __restrict__ deg, int E2) {
    int e = blockIdx.x * blockDim.x + threadIdx.x;
    if (e < E2) atomicAdd(&deg[ei[E2 + e]], 1.0f);
}

// ---------------- Stage 4: deg -> dinv in place ----------------
__global__ void k_dinv(float* __restrict__ deg, int G) {
    int g = blockIdx.x * blockDim.x + threadIdx.x;
    if (g < G) {
        float d = deg[g];
        deg[g] = (d > 0.f) ? (1.0f / sqrtf(fmaxf(d, 1.0f))) : 0.f;
    }
}

// ---------------- Stage 5: edge scatter s[b,dst] += xcat[b,src]*norm ----------------
__global__ void k_scatter(const float* __restrict__ xcat, const int* __restrict__ ei,
                          const float* __restrict__ dinv, float* __restrict__ s,
                          int G, int E2, int total) {
    int idx = blockIdx.x * blockDim.x + threadIdx.x;
    if (idx >= total) return;
    int b = idx / E2;
    int e = idx - b * E2;
    int src = ei[e], dst = ei[E2 + e];
    float norm = dinv[src] * dinv[dst];
    atomicAdd(&s[(size_t)b * G + dst], xcat[(size_t)b * G + src] * norm);
}

// ---------------- Stage 6: g = relu(w_conv*s + b_conv) -> d_out[B*G : B*G + 2*B*G) ----------------
__global__ void k_gfin(const float* __restrict__ s, const float* __restrict__ w_conv,
                       const float* __restrict__ b_conv, float* __restrict__ gout, int BG) {
    int i = blockIdx.x * blockDim.x + threadIdx.x;   // i = b*G + n
    if (i >= BG) return;
    float sv = s[i];
    float g0 = sv * w_conv[0] + b_conv[0];
    float g1 = sv * w_conv[1] + b_conv[1];
    gout[2 * (size_t)i + 0] = g0 > 0.f ? g0 : 0.f;   // b*2G + 2n + f == 2*i + f
    gout[2 * (size_t)i + 1] = g1 > 0.f ? g1 : 0.f;
}

// ---------------- Stage 7: out = g @ w_out + b_out ----------------
__global__ void k_out(const float* __restrict__ gmat, const float* __restrict__ w_out,
                      const float* __restrict__ b_out, float* __restrict__ out, int G2) {
    int b = blockIdx.x;
    float a0 = 0.f, a1 = 0.f, a2 = 0.f;
    for (int i = threadIdx.x; i < G2; i += blockDim.x) {
        float gv = gmat[(size_t)b * G2 + i];
        a0 += gv * w_out[3 * i + 0];
        a1 += gv * w_out[3 * i + 1];
        a2 += gv * w_out[3 * i + 2];
    }
    __shared__ float red[3][256];
    red[0][threadIdx.x] = a0; red[1][threadIdx.x] = a1; red[2][threadIdx.x] = a2;
    __syncthreads();
    for (int s = blockDim.x / 2; s > 0; s >>= 1) {
        if ((int)threadIdx.x < s) {
            red[0][threadIdx.x] += red[0][threadIdx.x + s];
            red[1][threadIdx.x] += red[1][threadIdx.x + s];
            red[2][threadIdx.x] += red[2][threadIdx.x + s];
        }
        __syncthreads();
    }
    if (threadIdx.x == 0) {
        out[b * 3 + 0] = red[0][0] + b_out[0];
        out[b * 3 + 1] = red[1][0] + b_out[1];
        out[b * 3 + 2] = red[2][0] + b_out[2];
    }
}

extern "C" void kernel_launch(void* const* d_in, const int* in_sizes, int n_in,
                              void* d_out, int out_size, void* d_ws, size_t ws_size,
                              hipStream_t stream) {
    const float* x        = (const float*)d_in[0];
    const int*   gene_ids = (const int*)d_in[1];
    const float* w_sub    = (const float*)d_in[2];
    const float* b_sub    = (const float*)d_in[3];
    const int*   ei       = (const int*)d_in[4];
    const float* w_conv   = (const float*)d_in[5];
    const float* b_conv   = (const float*)d_in[6];
    const float* w_out    = (const float*)d_in[7];
    const float* b_out    = (const float*)d_in[8];

    const int G  = in_sizes[3];
    const int T  = in_sizes[1];
    const int TF = in_sizes[2] / T;
    const int B  = in_sizes[0] / (TF * T);
    const int E2 = in_sizes[4] / 2;     // 2E
    const int BG = B * G;
    const int G2 = 2 * G;

    // workspace layout (floats): acc[BG] | deg/dinv[G] | s[BG]
    float* acc = (float*)d_ws;
    float* deg = acc + BG;
    float* s   = deg + G;
    size_t zero_bytes = (size_t)(BG + G + BG) * sizeof(float);
    hipMemsetAsync(d_ws, 0, zero_bytes, stream);

    float* out_xcat = (float*)d_out;          // [B, G]
    float* out_g    = out_xcat + BG;          // [B, 2G]
    float* out_fin  = out_g + (size_t)B * G2; // [B, 3]

    // Stage 1
    {
        int tthreads = (T + 3) / 4;
        dim3 grid((tthreads + 255) / 256, B);
        k_subnet<<<grid, 256, 0, stream>>>(x, w_sub, gene_ids, acc, TF, T, G);
    }
    // Stage 2
    k_xcat<<<(BG + 255) / 256, 256, 0, stream>>>(acc, b_sub, out_xcat, BG, G);
    // Stage 3
    k_deg<<<(E2 + 255) / 256, 256, 0, stream>>>(ei, deg, E2);
    // Stage 4
    k_dinv<<<(G + 255) / 256, 256, 0, stream>>>(deg, G);
    // Stage 5
    {
        int total = B * E2;
        k_scatter<<<(total + 255) / 256, 256, 0, stream>>>(out_xcat, ei, deg, s, G, E2, total);
    }
    // Stage 6
    k_gfin<<<(BG + 255) / 256, 256, 0, stream>>>(s, w_conv, b_conv, out_g, BG);
    // Stage 7
    k_out<<<B, 256, 0, stream>>>(out_g, w_out, b_out, out_fin, G2);
}